// Round 4
// baseline (3590.800 us; speedup 1.0000x reference)
//
#include <hip/hip_runtime.h>
#include <cstdint>
#include <cstddef>

// ---------------------------------------------------------------------------
// TLSTM: B=64, S=512, I=256, H=256
// R4 = R3 with the deadlock fixed: release tag now includes the quarter
// offset (tg + p*64 + q*16); R3 wrote all four quarters to slot 0 and the
// poll on slots 1..3 spun forever.
// Weights register-resident (named uint4 + asm pins, lb(320,2)).
// 4 blocks per batch (bid = q*64+b, partners congruent mod 8 -> same XCD).
// ---------------------------------------------------------------------------

#define B_   64
#define S_   512
#define H_   256
#define BSH_ ((size_t)B_ * S_ * H_)  // 8388608

typedef _Float16 f16;
typedef _Float16 f16x2 __attribute__((ext_vector_type(2)));
typedef _Float16 f16x8 __attribute__((ext_vector_type(8)));
typedef short    s16x8 __attribute__((ext_vector_type(8)));
typedef float    f32x4 __attribute__((ext_vector_type(4)));

static __device__ __forceinline__ unsigned short f32_to_bf16(float f) {
    union { float f; uint32_t u; } v; v.f = f;
    uint32_t u = v.u;
    u += 0x7fffu + ((u >> 16) & 1u);   // RTNE
    return (unsigned short)(u >> 16);
}

static __device__ __forceinline__ float fdot2f(f16x2 a, f16x2 b, float c) {
#if __has_builtin(__builtin_amdgcn_fdot2)
    return __builtin_amdgcn_fdot2(a, b, c, false);
#else
    return c + (float)a[0] * (float)b[0] + (float)a[1] * (float)b[1];
#endif
}

static __device__ __forceinline__ float sigm(float z) {
    return 1.0f / (1.0f + __expf(-z));
}
static __device__ __forceinline__ float tanh_fast(float z) {
    float e = __expf(-2.0f * fabsf(z));
    float t = (1.0f - e) / (1.0f + e);
    return z >= 0.0f ? t : -t;
}

// ---------------------------------------------------------------------------
// prep: W4 (bf16, [1024][256]) + fused bias4 (Wg_b + b_g + Ug_b)
// ---------------------------------------------------------------------------
__global__ void prep_w4(const float* __restrict__ Wi, const float* __restrict__ Wf,
                        const float* __restrict__ Wo, const float* __restrict__ Wc,
                        const float* __restrict__ Wib, const float* __restrict__ Wfb,
                        const float* __restrict__ Wob, const float* __restrict__ Wcb,
                        const float* __restrict__ Uib, const float* __restrict__ Ufb,
                        const float* __restrict__ Uob, const float* __restrict__ Ucb,
                        const float* __restrict__ bi,  const float* __restrict__ bf_,
                        const float* __restrict__ bo,  const float* __restrict__ bc,
                        unsigned short* __restrict__ W4, float* __restrict__ bias4) {
    const int n = blockIdx.x;        // 0..1023
    const int k = threadIdx.x;       // 0..255
    const int g = n >> 8, o = n & 255;
    const float* W = (g == 0) ? Wi : (g == 1) ? Wf : (g == 2) ? Wo : Wc;
    W4[n * 256 + k] = f32_to_bf16(W[o * 256 + k]);
    if (k == 0) {
        const float* wb = (g == 0) ? Wib : (g == 1) ? Wfb : (g == 2) ? Wob : Wcb;
        const float* ub = (g == 0) ? Uib : (g == 1) ? Ufb : (g == 2) ? Uob : Ucb;
        const float* sb = (g == 0) ? bi  : (g == 1) ? bf_ : (g == 2) ? bo  : bc;
        bias4[n] = wb[o] + ub[o] + sb[o];
    }
}

// ---------------------------------------------------------------------------
// prep: Wpk f16 row-major [1280][256], rows n = g*256 + o, g in [Ui,Uf,Uo,Uc,Wd]
// ---------------------------------------------------------------------------
__global__ void prep_wrow(const float* __restrict__ Ui, const float* __restrict__ Uf,
                          const float* __restrict__ Uo, const float* __restrict__ Uc,
                          const float* __restrict__ Wd, f16* __restrict__ Wpk) {
    const int n = blockIdx.x;        // 0..1279
    const int k = threadIdx.x;       // 0..255
    const int g = n >> 8, o = n & 255;
    const float* U = (g == 0) ? Ui : (g == 1) ? Uf : (g == 2) ? Uo : (g == 3) ? Uc : Wd;
    Wpk[(size_t)n * 256 + k] = (f16)U[o * 256 + k];
}

// zero the sync tags (runs every launch; graph replays it)
__global__ void prep_zero(unsigned int* __restrict__ tags) {
    tags[blockIdx.x * 256 + threadIdx.x] = 0u;
}

// ---------------------------------------------------------------------------
// Projection GEMM (unchanged): Xbuf[m][n] f16, bias folded.
// ---------------------------------------------------------------------------
__global__ __launch_bounds__(256) void proj_gemm(const float* __restrict__ X,
        const unsigned short* __restrict__ W4, const float* __restrict__ bias4,
        f16* __restrict__ Xbuf) {
    __shared__ __align__(16) unsigned short a_s[64 * 40];
    __shared__ __align__(16) unsigned short b_s[64 * 40];
    const int bid = blockIdx.x;
    const int m0 = (bid >> 4) * 64;
    const int n0 = (bid & 15) * 64;
    const int tid  = threadIdx.x;
    const int lane = tid & 63;
    const int w    = tid >> 6;
    const int srow = tid >> 2;
    const int scol = (tid & 3) * 8;
    const int r  = lane & 15;
    const int kg = lane >> 4;

    f32x4 acc[4] = {{0,0,0,0},{0,0,0,0},{0,0,0,0},{0,0,0,0}};

    for (int kt = 0; kt < 8; ++kt) {
        const int k0 = kt * 32;
        float4 av0 = *reinterpret_cast<const float4*>(X + (size_t)(m0 + srow) * 256 + k0 + scol);
        float4 av1 = *reinterpret_cast<const float4*>(X + (size_t)(m0 + srow) * 256 + k0 + scol + 4);
        union { unsigned short us[8]; uint4 v; } pk;
        pk.us[0] = f32_to_bf16(av0.x); pk.us[1] = f32_to_bf16(av0.y);
        pk.us[2] = f32_to_bf16(av0.z); pk.us[3] = f32_to_bf16(av0.w);
        pk.us[4] = f32_to_bf16(av1.x); pk.us[5] = f32_to_bf16(av1.y);
        pk.us[6] = f32_to_bf16(av1.z); pk.us[7] = f32_to_bf16(av1.w);
        *reinterpret_cast<uint4*>(a_s + srow * 40 + scol) = pk.v;
        uint4 bv = *reinterpret_cast<const uint4*>(W4 + (size_t)(n0 + srow) * 256 + k0 + scol);
        *reinterpret_cast<uint4*>(b_s + srow * 40 + scol) = bv;
        __syncthreads();

        s16x8 af = *reinterpret_cast<const s16x8*>(a_s + (w * 16 + r) * 40 + kg * 8);
        #pragma unroll
        for (int nt = 0; nt < 4; ++nt) {
            s16x8 bfr = *reinterpret_cast<const s16x8*>(b_s + (nt * 16 + r) * 40 + kg * 8);
            acc[nt] = __builtin_amdgcn_mfma_f32_16x16x32_bf16(af, bfr, acc[nt], 0, 0, 0);
        }
        __syncthreads();
    }
    #pragma unroll
    for (int nt = 0; nt < 4; ++nt) {
        const int n = n0 + nt * 16 + r;
        const float bn = bias4[n];
        #pragma unroll
        for (int reg = 0; reg < 4; ++reg) {
            const int m = m0 + w * 16 + kg * 4 + reg;
            Xbuf[(size_t)m * 1024 + n] = (f16)(acc[nt][reg] + bn);
        }
    }
}

// ---------------------------------------------------------------------------
// Recurrence.
// ---------------------------------------------------------------------------
#define W_ALL(F) F(0) F(1) F(2) F(3) F(4) F(5) F(6) F(7) \
                 F(8) F(9) F(10) F(11) F(12) F(13) F(14) F(15) \
                 F(16) F(17) F(18) F(19) F(20) F(21) F(22) F(23) \
                 F(24) F(25) F(26) F(27) F(28) F(29) F(30) F(31)

__global__ __launch_bounds__(320, 2) void recur(const float* __restrict__ tsp,
        const f16* __restrict__ Wpk, const f16* __restrict__ Xbuf,
        const float* __restrict__ Wdb, const float* __restrict__ bdv,
        f16* __restrict__ hx, f16* __restrict__ cx,
        unsigned int* __restrict__ tags, float* __restrict__ out) {
    __shared__ __align__(16) f16 hv_f16[512];   // [0..255]=h, [256..511]=c
    __shared__ float pre_s[320];

    const int tid = threadIdx.x;
    const int bid = blockIdx.x;
    const int q = bid >> 6;          // weight-row quarter 0..3
    const int b = bid & 63;          // batch
    const int g = tid >> 6;          // matrix 0..4 (i,f,o,c,d)
    const int r = tid & 63;
    const int n = g * 256 + q * 64 + r;   // global weight row

    // ---- load this thread's weight row into named registers (once) ----
    const uint4* wsrc = reinterpret_cast<const uint4*>(Wpk + (size_t)n * 256);
#define DECLW(i) uint4 W##i = wsrc[i];
    W_ALL(DECLW)
#undef DECLW
    // pin: forces all 128 dwords live in VGPRs here; defeats demotion to scratch
#define PINW(i) asm volatile("" : "+v"(W##i.x), "+v"(W##i.y), "+v"(W##i.z), "+v"(W##i.w));
    W_ALL(PINW)
#undef PINW

    // ---- init state ----
    if (tid < 256) { hv_f16[tid] = (f16)0; hv_f16[256 + tid] = (f16)0; }
    const int j = q * 64 + r;        // hidden index (wave 0 threads)
    float cj = 0.0f, bD = 0.0f;
    if (tid < 64) bD = Wdb[j] + bdv[j];
    __syncthreads();

    const f16* hbase = hv_f16 + ((g == 4) ? 256 : 0);   // Wd rows consume c
    unsigned int* tg = tags + (size_t)b * 128;          // [parity][4 q-slots x 64B]
    f16* hxb = hx + (size_t)b * 512;                    // [parity][256]
    f16* cxb = cx + (size_t)b * 512;

    for (int s = 0; s < 512; ++s) {
        // prefetch x-projections + timestamp (consumed after barrier A)
        float xi = 0.f, xf = 0.f, xo = 0.f, xc = 0.f, ts = 0.f;
        const size_t m = (size_t)b * 512 + s;
        if (tid < 64) {
            const f16* xp = Xbuf + m * 1024 + j;
            xi = (float)xp[0];   xf = (float)xp[256];
            xo = (float)xp[512]; xc = (float)xp[768];
            ts = tsp[m];
        }

        // ---- matvec from registers against LDS-broadcast h/c ----
        float a0 = 0.f, a1 = 0.f, a2 = 0.f, a3 = 0.f;
#define DOTW(i) { f16x8 hv = *reinterpret_cast<const f16x8*>(hbase + (i) * 8); \
        a0 = fdot2f(__builtin_bit_cast(f16x2, W##i.x), __builtin_shufflevector(hv, hv, 0, 1), a0); \
        a1 = fdot2f(__builtin_bit_cast(f16x2, W##i.y), __builtin_shufflevector(hv, hv, 2, 3), a1); \
        a2 = fdot2f(__builtin_bit_cast(f16x2, W##i.z), __builtin_shufflevector(hv, hv, 4, 5), a2); \
        a3 = fdot2f(__builtin_bit_cast(f16x2, W##i.w), __builtin_shufflevector(hv, hv, 6, 7), a3); }
        W_ALL(DOTW)
#undef DOTW
        const float myPre = (a0 + a1) + (a2 + a3);
        pre_s[tid] = myPre;
        __syncthreads();                               // A

        const int p = s & 1;
        if (tid < 64) {
            // ---- gates (uses own Ui preact from register) ----
            float T    = 1.0f / __logf(ts + 2.7183f);
            float CST  = tanh_fast(pre_s[256 + tid] + bD);
            float cdec = cj + (T - 1.0f) * CST;
            float ig = sigm(xi + myPre);
            float fg = sigm(xf + pre_s[64 + tid]);
            float og = sigm(xo + pre_s[128 + tid]);
            float Cn = tanh_fast(xc + pre_s[192 + tid]);
            cj = fg * cdec + ig * Cn;
            float hn = og * tanh_fast(cj);

            if (s != 511) {
                // publish h/c (L2), then release own quarter slot (lane 0)
                hxb[p * 256 + j] = (f16)hn;
                cxb[p * 256 + j] = (f16)cj;
                if (tid == 0)
                    __hip_atomic_store(tg + p * 64 + q * 16, (unsigned)(s + 1),
                                       __ATOMIC_RELEASE, __HIP_MEMORY_SCOPE_AGENT);
            }
            // out stores issued after release: HBM drain overlaps polling
            const size_t oi = m * 256 + j;
            out[oi]            = hn;
            out[BSH_ + oi]     = hn;
            out[2 * BSH_ + oi] = cj;

            if (s != 511) {
                // acquire-poll partners (lanes 0..3, one slot/line each)
                if (tid < 4) {
                    while (__hip_atomic_load(tg + p * 64 + tid * 16,
                                             __ATOMIC_ACQUIRE, __HIP_MEMORY_SCOPE_AGENT)
                           < (unsigned)(s + 1))
                        __builtin_amdgcn_s_sleep(1);
                }
                // stage exchanged h/c into LDS (lanes 0-31: h, 32-63: c)
                if (tid < 32) {
                    uint4 v = *reinterpret_cast<const uint4*>(hxb + p * 256 + tid * 8);
                    *reinterpret_cast<uint4*>(&hv_f16[tid * 8]) = v;
                } else {
                    const int u = tid - 32;
                    uint4 v = *reinterpret_cast<const uint4*>(cxb + p * 256 + u * 8);
                    *reinterpret_cast<uint4*>(&hv_f16[256 + u * 8]) = v;
                }
            }
        }
        __syncthreads();                               // C
    }
    // final pin keeps weights formally live through the loop
#define PINW2(i) asm volatile("" :: "v"(W##i.x), "v"(W##i.y), "v"(W##i.z), "v"(W##i.w));
    W_ALL(PINW2)
#undef PINW2
}

// ---------------------------------------------------------------------------
extern "C" void kernel_launch(void* const* d_in, const int* in_sizes, int n_in,
                              void* d_out, int out_size, void* d_ws, size_t ws_size,
                              hipStream_t stream) {
    const float* inputs = (const float*)d_in[0];
    const float* tsp    = (const float*)d_in[1];
    const float* Wi_w = (const float*)d_in[2],  * Wi_b = (const float*)d_in[3];
    const float* Ui_w = (const float*)d_in[4],  * Ui_b = (const float*)d_in[5];
    const float* Wf_w = (const float*)d_in[6],  * Wf_b = (const float*)d_in[7];
    const float* Uf_w = (const float*)d_in[8],  * Uf_b = (const float*)d_in[9];
    const float* Wo_w = (const float*)d_in[10], * Wo_b = (const float*)d_in[11];
    const float* Uo_w = (const float*)d_in[12], * Uo_b = (const float*)d_in[13];
    const float* Wc_w = (const float*)d_in[14], * Wc_b = (const float*)d_in[15];
    const float* Uc_w = (const float*)d_in[16], * Uc_b = (const float*)d_in[17];
    const float* Wd_w = (const float*)d_in[18], * Wd_b = (const float*)d_in[19];
    const float* bi = (const float*)d_in[20], * bf_ = (const float*)d_in[21];
    const float* bo = (const float*)d_in[22], * bc  = (const float*)d_in[23];
    const float* bd = (const float*)d_in[24];

    // workspace layout (16B-aligned):
    //   Xbuf  f16  [32768][1024]   67,108,864 B @ 0
    //   W4    bf16 [1024][256]        524,288 B @ 67,108,864
    //   bias4 f32  [1024]               4,096 B @ 67,633,152
    //   Wpk   f16  [1280][256]        655,360 B @ 67,637,248
    //   hx    f16  [64][2][256]        65,536 B @ 68,292,608
    //   cx    f16  [64][2][256]        65,536 B @ 68,358,144
    //   tags  u32  [64][2][4][16]      32,768 B @ 68,423,680   (64B per slot)
    char* ws = (char*)d_ws;
    f16*            Xbuf  = (f16*)ws;
    unsigned short* W4    = (unsigned short*)(ws + 67108864);
    float*          bias4 = (float*)(ws + 67633152);
    f16*            Wpk   = (f16*)(ws + 67637248);
    f16*            hx    = (f16*)(ws + 68292608);
    f16*            cx    = (f16*)(ws + 68358144);
    unsigned int*   tags  = (unsigned int*)(ws + 68423680);

    prep_w4<<<1024, 256, 0, stream>>>(Wi_w, Wf_w, Wo_w, Wc_w,
                                      Wi_b, Wf_b, Wo_b, Wc_b,
                                      Ui_b, Uf_b, Uo_b, Uc_b,
                                      bi, bf_, bo, bc, W4, bias4);
    prep_wrow<<<1280, 256, 0, stream>>>(Ui_w, Uf_w, Uo_w, Uc_w, Wd_w, Wpk);
    prep_zero<<<32, 256, 0, stream>>>(tags);
    proj_gemm<<<8192, 256, 0, stream>>>(inputs, W4, bias4, Xbuf);
    recur<<<256, 320, 0, stream>>>(tsp, Wpk, Xbuf, Wd_b, bd, hx, cx, tags, (float*)d_out);
}

// Round 5
// 3544.267 us; speedup vs baseline: 1.0131x; 1.0131x over previous
//
#include <hip/hip_runtime.h>
#include <cstdint>
#include <cstddef>

// ---------------------------------------------------------------------------
// TLSTM: B=64, S=512, I=256, H=256
// R5 = R4 with ONE change: kernel attribute amdgpu_waves_per_eu(1,2) replaces
// __launch_bounds__(320,2). Theory: R2/R4's weight spill (VGPR_Count 84-88 ~
// 512/6) was the register allocator's high-occupancy TARGET heuristic, which
// launch_bounds' min-waves floor does not cap. max=2 waves/EU caps the target
// -> 256 VGPR budget -> the 128 weight dwords + ~60 working regs fit.
// ---------------------------------------------------------------------------

#define B_   64
#define S_   512
#define H_   256
#define BSH_ ((size_t)B_ * S_ * H_)  // 8388608

typedef _Float16 f16;
typedef _Float16 f16x2 __attribute__((ext_vector_type(2)));
typedef _Float16 f16x8 __attribute__((ext_vector_type(8)));
typedef short    s16x8 __attribute__((ext_vector_type(8)));
typedef float    f32x4 __attribute__((ext_vector_type(4)));

static __device__ __forceinline__ unsigned short f32_to_bf16(float f) {
    union { float f; uint32_t u; } v; v.f = f;
    uint32_t u = v.u;
    u += 0x7fffu + ((u >> 16) & 1u);   // RTNE
    return (unsigned short)(u >> 16);
}

static __device__ __forceinline__ float fdot2f(f16x2 a, f16x2 b, float c) {
#if __has_builtin(__builtin_amdgcn_fdot2)
    return __builtin_amdgcn_fdot2(a, b, c, false);
#else
    return c + (float)a[0] * (float)b[0] + (float)a[1] * (float)b[1];
#endif
}

static __device__ __forceinline__ float sigm(float z) {
    return 1.0f / (1.0f + __expf(-z));
}
static __device__ __forceinline__ float tanh_fast(float z) {
    float e = __expf(-2.0f * fabsf(z));
    float t = (1.0f - e) / (1.0f + e);
    return z >= 0.0f ? t : -t;
}

// ---------------------------------------------------------------------------
// prep: W4 (bf16, [1024][256]) + fused bias4 (Wg_b + b_g + Ug_b)
// ---------------------------------------------------------------------------
__global__ void prep_w4(const float* __restrict__ Wi, const float* __restrict__ Wf,
                        const float* __restrict__ Wo, const float* __restrict__ Wc,
                        const float* __restrict__ Wib, const float* __restrict__ Wfb,
                        const float* __restrict__ Wob, const float* __restrict__ Wcb,
                        const float* __restrict__ Uib, const float* __restrict__ Ufb,
                        const float* __restrict__ Uob, const float* __restrict__ Ucb,
                        const float* __restrict__ bi,  const float* __restrict__ bf_,
                        const float* __restrict__ bo,  const float* __restrict__ bc,
                        unsigned short* __restrict__ W4, float* __restrict__ bias4) {
    const int n = blockIdx.x;        // 0..1023
    const int k = threadIdx.x;       // 0..255
    const int g = n >> 8, o = n & 255;
    const float* W = (g == 0) ? Wi : (g == 1) ? Wf : (g == 2) ? Wo : Wc;
    W4[n * 256 + k] = f32_to_bf16(W[o * 256 + k]);
    if (k == 0) {
        const float* wb = (g == 0) ? Wib : (g == 1) ? Wfb : (g == 2) ? Wob : Wcb;
        const float* ub = (g == 0) ? Uib : (g == 1) ? Ufb : (g == 2) ? Uob : Ucb;
        const float* sb = (g == 0) ? bi  : (g == 1) ? bf_ : (g == 2) ? bo  : bc;
        bias4[n] = wb[o] + ub[o] + sb[o];
    }
}

// ---------------------------------------------------------------------------
// prep: Wpk f16 row-major [1280][256], rows n = g*256 + o, g in [Ui,Uf,Uo,Uc,Wd]
// ---------------------------------------------------------------------------
__global__ void prep_wrow(const float* __restrict__ Ui, const float* __restrict__ Uf,
                          const float* __restrict__ Uo, const float* __restrict__ Uc,
                          const float* __restrict__ Wd, f16* __restrict__ Wpk) {
    const int n = blockIdx.x;        // 0..1279
    const int k = threadIdx.x;       // 0..255
    const int g = n >> 8, o = n & 255;
    const float* U = (g == 0) ? Ui : (g == 1) ? Uf : (g == 2) ? Uo : (g == 3) ? Uc : Wd;
    Wpk[(size_t)n * 256 + k] = (f16)U[o * 256 + k];
}

// zero the sync tags (runs every launch; graph replays it)
__global__ void prep_zero(unsigned int* __restrict__ tags) {
    tags[blockIdx.x * 256 + threadIdx.x] = 0u;
}

// ---------------------------------------------------------------------------
// Projection GEMM (unchanged): Xbuf[m][n] f16, bias folded.
// ---------------------------------------------------------------------------
__global__ __launch_bounds__(256) void proj_gemm(const float* __restrict__ X,
        const unsigned short* __restrict__ W4, const float* __restrict__ bias4,
        f16* __restrict__ Xbuf) {
    __shared__ __align__(16) unsigned short a_s[64 * 40];
    __shared__ __align__(16) unsigned short b_s[64 * 40];
    const int bid = blockIdx.x;
    const int m0 = (bid >> 4) * 64;
    const int n0 = (bid & 15) * 64;
    const int tid  = threadIdx.x;
    const int lane = tid & 63;
    const int w    = tid >> 6;
    const int srow = tid >> 2;
    const int scol = (tid & 3) * 8;
    const int r  = lane & 15;
    const int kg = lane >> 4;

    f32x4 acc[4] = {{0,0,0,0},{0,0,0,0},{0,0,0,0},{0,0,0,0}};

    for (int kt = 0; kt < 8; ++kt) {
        const int k0 = kt * 32;
        float4 av0 = *reinterpret_cast<const float4*>(X + (size_t)(m0 + srow) * 256 + k0 + scol);
        float4 av1 = *reinterpret_cast<const float4*>(X + (size_t)(m0 + srow) * 256 + k0 + scol + 4);
        union { unsigned short us[8]; uint4 v; } pk;
        pk.us[0] = f32_to_bf16(av0.x); pk.us[1] = f32_to_bf16(av0.y);
        pk.us[2] = f32_to_bf16(av0.z); pk.us[3] = f32_to_bf16(av0.w);
        pk.us[4] = f32_to_bf16(av1.x); pk.us[5] = f32_to_bf16(av1.y);
        pk.us[6] = f32_to_bf16(av1.z); pk.us[7] = f32_to_bf16(av1.w);
        *reinterpret_cast<uint4*>(a_s + srow * 40 + scol) = pk.v;
        uint4 bv = *reinterpret_cast<const uint4*>(W4 + (size_t)(n0 + srow) * 256 + k0 + scol);
        *reinterpret_cast<uint4*>(b_s + srow * 40 + scol) = bv;
        __syncthreads();

        s16x8 af = *reinterpret_cast<const s16x8*>(a_s + (w * 16 + r) * 40 + kg * 8);
        #pragma unroll
        for (int nt = 0; nt < 4; ++nt) {
            s16x8 bfr = *reinterpret_cast<const s16x8*>(b_s + (nt * 16 + r) * 40 + kg * 8);
            acc[nt] = __builtin_amdgcn_mfma_f32_16x16x32_bf16(af, bfr, acc[nt], 0, 0, 0);
        }
        __syncthreads();
    }
    #pragma unroll
    for (int nt = 0; nt < 4; ++nt) {
        const int n = n0 + nt * 16 + r;
        const float bn = bias4[n];
        #pragma unroll
        for (int reg = 0; reg < 4; ++reg) {
            const int m = m0 + w * 16 + kg * 4 + reg;
            Xbuf[(size_t)m * 1024 + n] = (f16)(acc[nt][reg] + bn);
        }
    }
}

// ---------------------------------------------------------------------------
// Recurrence.
// ---------------------------------------------------------------------------
#define W_ALL(F) F(0) F(1) F(2) F(3) F(4) F(5) F(6) F(7) \
                 F(8) F(9) F(10) F(11) F(12) F(13) F(14) F(15) \
                 F(16) F(17) F(18) F(19) F(20) F(21) F(22) F(23) \
                 F(24) F(25) F(26) F(27) F(28) F(29) F(30) F(31)

__global__ __launch_bounds__(320)
__attribute__((amdgpu_waves_per_eu(1, 2)))   // cap allocator's occupancy TARGET
void recur(const float* __restrict__ tsp,
        const f16* __restrict__ Wpk, const f16* __restrict__ Xbuf,
        const float* __restrict__ Wdb, const float* __restrict__ bdv,
        f16* __restrict__ hx, f16* __restrict__ cx,
        unsigned int* __restrict__ tags, float* __restrict__ out) {
    __shared__ __align__(16) f16 hv_f16[512];   // [0..255]=h, [256..511]=c
    __shared__ float pre_s[320];

    const int tid = threadIdx.x;
    const int bid = blockIdx.x;
    const int q = bid >> 6;          // weight-row quarter 0..3
    const int b = bid & 63;          // batch
    const int g = tid >> 6;          // matrix 0..4 (i,f,o,c,d)
    const int r = tid & 63;
    const int n = g * 256 + q * 64 + r;   // global weight row

    // ---- load this thread's weight row into named registers (once) ----
    const uint4* wsrc = reinterpret_cast<const uint4*>(Wpk + (size_t)n * 256);
#define DECLW(i) uint4 W##i = wsrc[i];
    W_ALL(DECLW)
#undef DECLW
#define PINW(i) asm volatile("" : "+v"(W##i.x), "+v"(W##i.y), "+v"(W##i.z), "+v"(W##i.w));
    W_ALL(PINW)
#undef PINW

    // ---- init state ----
    if (tid < 256) { hv_f16[tid] = (f16)0; hv_f16[256 + tid] = (f16)0; }
    const int j = q * 64 + r;        // hidden index (wave 0 threads)
    float cj = 0.0f, bD = 0.0f;
    if (tid < 64) bD = Wdb[j] + bdv[j];
    __syncthreads();

    const f16* hbase = hv_f16 + ((g == 4) ? 256 : 0);   // Wd rows consume c
    unsigned int* tg = tags + (size_t)b * 128;          // [parity][4 q-slots x 64B]
    f16* hxb = hx + (size_t)b * 512;                    // [parity][256]
    f16* cxb = cx + (size_t)b * 512;

    for (int s = 0; s < 512; ++s) {
        // prefetch x-projections + timestamp (consumed after barrier A)
        float xi = 0.f, xf = 0.f, xo = 0.f, xc = 0.f, ts = 0.f;
        const size_t m = (size_t)b * 512 + s;
        if (tid < 64) {
            const f16* xp = Xbuf + m * 1024 + j;
            xi = (float)xp[0];   xf = (float)xp[256];
            xo = (float)xp[512]; xc = (float)xp[768];
            ts = tsp[m];
        }

        // ---- matvec from registers against LDS-broadcast h/c ----
        float a0 = 0.f, a1 = 0.f, a2 = 0.f, a3 = 0.f;
#define DOTW(i) { f16x8 hv = *reinterpret_cast<const f16x8*>(hbase + (i) * 8); \
        a0 = fdot2f(__builtin_bit_cast(f16x2, W##i.x), __builtin_shufflevector(hv, hv, 0, 1), a0); \
        a1 = fdot2f(__builtin_bit_cast(f16x2, W##i.y), __builtin_shufflevector(hv, hv, 2, 3), a1); \
        a2 = fdot2f(__builtin_bit_cast(f16x2, W##i.z), __builtin_shufflevector(hv, hv, 4, 5), a2); \
        a3 = fdot2f(__builtin_bit_cast(f16x2, W##i.w), __builtin_shufflevector(hv, hv, 6, 7), a3); }
        W_ALL(DOTW)
#undef DOTW
        const float myPre = (a0 + a1) + (a2 + a3);
        pre_s[tid] = myPre;
        __syncthreads();                               // A

        const int p = s & 1;
        if (tid < 64) {
            // ---- gates (uses own Ui preact from register) ----
            float T    = 1.0f / __logf(ts + 2.7183f);
            float CST  = tanh_fast(pre_s[256 + tid] + bD);
            float cdec = cj + (T - 1.0f) * CST;
            float ig = sigm(xi + myPre);
            float fg = sigm(xf + pre_s[64 + tid]);
            float og = sigm(xo + pre_s[128 + tid]);
            float Cn = tanh_fast(xc + pre_s[192 + tid]);
            cj = fg * cdec + ig * Cn;
            float hn = og * tanh_fast(cj);

            if (s != 511) {
                // publish h/c (L2), then release own quarter slot (lane 0)
                hxb[p * 256 + j] = (f16)hn;
                cxb[p * 256 + j] = (f16)cj;
                if (tid == 0)
                    __hip_atomic_store(tg + p * 64 + q * 16, (unsigned)(s + 1),
                                       __ATOMIC_RELEASE, __HIP_MEMORY_SCOPE_AGENT);
            }
            // out stores issued after release: HBM drain overlaps polling
            const size_t oi = m * 256 + j;
            out[oi]            = hn;
            out[BSH_ + oi]     = hn;
            out[2 * BSH_ + oi] = cj;

            if (s != 511) {
                // acquire-poll partners (lanes 0..3, one slot/line each)
                if (tid < 4) {
                    while (__hip_atomic_load(tg + p * 64 + tid * 16,
                                             __ATOMIC_ACQUIRE, __HIP_MEMORY_SCOPE_AGENT)
                           < (unsigned)(s + 1))
                        __builtin_amdgcn_s_sleep(1);
                }
                // stage exchanged h/c into LDS (lanes 0-31: h, 32-63: c)
                if (tid < 32) {
                    uint4 v = *reinterpret_cast<const uint4*>(hxb + p * 256 + tid * 8);
                    *reinterpret_cast<uint4*>(&hv_f16[tid * 8]) = v;
                } else {
                    const int u = tid - 32;
                    uint4 v = *reinterpret_cast<const uint4*>(cxb + p * 256 + u * 8);
                    *reinterpret_cast<uint4*>(&hv_f16[256 + u * 8]) = v;
                }
            }
        }
        __syncthreads();                               // C
    }
#define PINW2(i) asm volatile("" :: "v"(W##i.x), "v"(W##i.y), "v"(W##i.z), "v"(W##i.w));
    W_ALL(PINW2)
#undef PINW2
}

// ---------------------------------------------------------------------------
extern "C" void kernel_launch(void* const* d_in, const int* in_sizes, int n_in,
                              void* d_out, int out_size, void* d_ws, size_t ws_size,
                              hipStream_t stream) {
    const float* inputs = (const float*)d_in[0];
    const float* tsp    = (const float*)d_in[1];
    const float* Wi_w = (const float*)d_in[2],  * Wi_b = (const float*)d_in[3];
    const float* Ui_w = (const float*)d_in[4],  * Ui_b = (const float*)d_in[5];
    const float* Wf_w = (const float*)d_in[6],  * Wf_b = (const float*)d_in[7];
    const float* Uf_w = (const float*)d_in[8],  * Uf_b = (const float*)d_in[9];
    const float* Wo_w = (const float*)d_in[10], * Wo_b = (const float*)d_in[11];
    const float* Uo_w = (const float*)d_in[12], * Uo_b = (const float*)d_in[13];
    const float* Wc_w = (const float*)d_in[14], * Wc_b = (const float*)d_in[15];
    const float* Uc_w = (const float*)d_in[16], * Uc_b = (const float*)d_in[17];
    const float* Wd_w = (const float*)d_in[18], * Wd_b = (const float*)d_in[19];
    const float* bi = (const float*)d_in[20], * bf_ = (const float*)d_in[21];
    const float* bo = (const float*)d_in[22], * bc  = (const float*)d_in[23];
    const float* bd = (const float*)d_in[24];

    // workspace layout (16B-aligned):
    //   Xbuf  f16  [32768][1024]   67,108,864 B @ 0
    //   W4    bf16 [1024][256]        524,288 B @ 67,108,864
    //   bias4 f32  [1024]               4,096 B @ 67,633,152
    //   Wpk   f16  [1280][256]        655,360 B @ 67,637,248
    //   hx    f16  [64][2][256]        65,536 B @ 68,292,608
    //   cx    f16  [64][2][256]        65,536 B @ 68,358,144
    //   tags  u32  [64][2][4][16]      32,768 B @ 68,423,680   (64B per slot)
    char* ws = (char*)d_ws;
    f16*            Xbuf  = (f16*)ws;
    unsigned short* W4    = (unsigned short*)(ws + 67108864);
    float*          bias4 = (float*)(ws + 67633152);
    f16*            Wpk   = (f16*)(ws + 67637248);
    f16*            hx    = (f16*)(ws + 68292608);
    f16*            cx    = (f16*)(ws + 68358144);
    unsigned int*   tags  = (unsigned int*)(ws + 68423680);

    prep_w4<<<1024, 256, 0, stream>>>(Wi_w, Wf_w, Wo_w, Wc_w,
                                      Wi_b, Wf_b, Wo_b, Wc_b,
                                      Ui_b, Uf_b, Uo_b, Uc_b,
                                      bi, bf_, bo, bc, W4, bias4);
    prep_wrow<<<1280, 256, 0, stream>>>(Ui_w, Uf_w, Uo_w, Uc_w, Wd_w, Wpk);
    prep_zero<<<32, 256, 0, stream>>>(tags);
    proj_gemm<<<8192, 256, 0, stream>>>(inputs, W4, bias4, Xbuf);
    recur<<<256, 320, 0, stream>>>(tsp, Wpk, Xbuf, Wd_b, bd, hx, cx, tags, (float*)d_out);
}